// Round 5
// baseline (304.949 us; speedup 1.0000x reference)
//
#include <hip/hip_runtime.h>
#include <cstdint>
#include <cstddef>

#define IN_F 8192
#define OUT_F 8192
#define BATCH 512
#define KSPLIT 2
#define KSLICE (IN_F / KSPLIT) /* 4096 */
#define BK 64
#define TILES (KSLICE / BK) /* 64 */
#define BM 128
#define BN 256

typedef __bf16 bf16x8 __attribute__((ext_vector_type(8)));
typedef float floatx4 __attribute__((ext_vector_type(4)));

// fp32 -> bf16 round-to-nearest-even
__device__ __forceinline__ ushort f2bf(float f) {
  uint32_t u = __float_as_uint(f);
  u += 0x7FFFu + ((u >> 16) & 1u);
  return (ushort)(u >> 16);
}

// packed int (2 nibbles in low byte) -> bf16x2 of biased weights (q+136):
// low half = 0x4300|hi_nib (even k), high half = 0x4300|lo_nib (odd k)
__device__ __forceinline__ uint32_t dq(int p) {
  uint32_t u = (uint32_t)p;
  return (((u >> 4) & 0xFu) | ((u & 0xFu) << 16)) | 0x43004300u;
}

// async global->LDS, 16B/lane, LDS dest = wave-uniform base + lane*16
__device__ __forceinline__ void gl16(const void* g, uint32_t* l) {
  __builtin_amdgcn_global_load_lds(
      (const __attribute__((address_space(1))) uint32_t*)g,
      (__attribute__((address_space(3))) uint32_t*)l, 16, 0, 0);
}

// Pass 1: x fp32 -> bf16, per-slice rowsums (KSPLIT=2). Zeroes out only on
// the atomic-fallback path (zout != nullptr).
__global__ __launch_bounds__(256) void cvt_rowsum(const float* __restrict__ x,
                                                  ushort* __restrict__ xb,
                                                  float* __restrict__ rowsum,
                                                  float* __restrict__ zout) {
  const int b = blockIdx.x;
  const int t = threadIdx.x;
  const float4* xr = (const float4*)(x + (size_t)b * IN_F);
  ushort4* xo = (ushort4*)(xb + (size_t)b * IN_F);
  float s[2] = {0.f, 0.f};
#pragma unroll
  for (int i = 0; i < 8; ++i) {
    float4 v = xr[i * 256 + t];
    ushort4 o;
    o.x = f2bf(v.x); o.y = f2bf(v.y); o.z = f2bf(v.z); o.w = f2bf(v.w);
    xo[i * 256 + t] = o;
    if (zout) {
      float4 z = {0.f, 0.f, 0.f, 0.f};
      ((float4*)(zout + (size_t)b * OUT_F))[i * 256 + t] = z;
    }
    s[i >> 2] += __uint_as_float((uint32_t)o.x << 16) + __uint_as_float((uint32_t)o.y << 16)
               + __uint_as_float((uint32_t)o.z << 16) + __uint_as_float((uint32_t)o.w << 16);
  }
  __shared__ float red[4][2];
  const int lane = t & 63, wid = t >> 6;
#pragma unroll
  for (int j = 0; j < 2; ++j) {
    float v = s[j];
#pragma unroll
    for (int off = 32; off >= 1; off >>= 1) v += __shfl_down(v, off, 64);
    if (lane == 0) red[wid][j] = v;
  }
  __syncthreads();
  if (t < 2) rowsum[t * BATCH + b] = red[0][t] + red[1][t] + red[2][t] + red[3][t];
}

// Split-K(2) quantized GEMM, 128(m) x 256(n) x (BK=64), 512 thr, 8 waves
// (2m x 4n), per-wave 64x64 (acc[4][4]).
// m201-style fine-interleaved schedule: 2 phases per K-tile, each
//   {stage-issue share | ds_read frags | s_barrier | lgkmcnt(0) |
//    setprio(1) 16xMFMA setprio(0) | s_barrier}
// PREFETCH DEPTH 2: A quad-buffered LDS via gl16 (tile t+2 issued during t),
// B packed 2 tiles ahead in regs (pbN issued during t, written t+1, read t+2).
// One vmcnt(6) per tile boundary: retires gl16(t+1); the 6 ops of t+2
// (4 pb loads + 2 gl16) stay in flight across ALL barriers (T3+T4).
// XOR swizzle slot = chunk ^ (row&7) on A-gload source / B ds_write / reads
// (round-1-verified: bank conflicts -> ~0 on reads).
__global__ __launch_bounds__(512, 2) void qgemm(const ushort* __restrict__ xb,
                                                const int* __restrict__ pw,
                                                const float* __restrict__ scale,
                                                const float* __restrict__ rowsum,
                                                float* __restrict__ out,
                                                float* __restrict__ part) {
  __shared__ uint32_t As[4 * BM * 32];  // 4 bufs x 16 KB = 64 KB
  __shared__ uint32_t Bs[2 * BN * 32];  // 2 bufs x 32 KB = 64 KB

  const int tid = threadIdx.x;
  const int lane = tid & 63;
  const int w = tid >> 6;
  const int wm = w >> 2, wn = w & 3;
  const int lr = lane & 15, lq = lane >> 4;

  const int n0 = blockIdx.x * BN;
  const int m0 = blockIdx.y * BM;
  const int ks = blockIdx.z;

  // A gload: wave w instr j covers rows w*16+j*8+(l>>3), slot l&7 linear.
  // Slot p of row r holds chunk p ^ (r&7); r&7 == (l>>3)&7 -> fold into src.
  const char* aSrc = (const char*)xb
      + (size_t)(m0 + w * 16 + (lane >> 3)) * (IN_F * 2)
      + (size_t)ks * (KSLICE * 2)
      + (size_t)((((lane & 7) ^ ((lane >> 3) & 7)) * 16));
  uint32_t* aDst = As + (w * 16) * 32;  // + j*256 + buf*4096

  // B packed: thread t owns row rt = t>>1, chunks {c0,c0+1,c0+4,c0+5}
  const int rt = tid >> 1;
  const int c0 = (tid & 1) * 2;
  const int rk = rt & 7;
  const int* bSrc = pw + (size_t)(n0 + rt) * (IN_F / 2) + ks * (KSLICE / 2);

  // fragment read word-offsets (slot = (kh*4+lq) ^ (lr&7); kh applied as ^16)
  const int key = lr & 7;
  const int aOff = (wm * 64 + lr) * 32 + ((lq ^ key) * 4);
  const int bOff = (wn * 64 + lr) * 32 + ((lq ^ key) * 4);

  floatx4 acc[4][4] = {};

  auto stB = [&](int bow, int q, int4 p) {
    int4 u;
    u.x = dq(p.x); u.y = dq(p.y); u.z = dq(p.z); u.w = dq(p.w);
    *(int4*)(Bs + bow + rt * 32 + ((q ^ rk) * 4)) = u;
  };

#define DSREAD(kh, AO, BO)                                                   \
  _Pragma("unroll") for (int f = 0; f < 4; ++f)                              \
      av[f] = *(const bf16x8*)(As + (((aOff + f * 512) ^ ((kh)*16)) + (AO))); \
  _Pragma("unroll") for (int f = 0; f < 4; ++f)                              \
      bv[f] = *(const bf16x8*)(Bs + (((bOff + f * 512) ^ ((kh)*16)) + (BO)));
#define MFMA16()                                                             \
  __builtin_amdgcn_s_setprio(1);                                             \
  _Pragma("unroll") for (int fm = 0; fm < 4; ++fm)                           \
      _Pragma("unroll") for (int fn = 0; fn < 4; ++fn)                       \
          acc[fm][fn] = __builtin_amdgcn_mfma_f32_16x16x32_bf16(             \
              av[fm], bv[fn], acc[fm][fn], 0, 0, 0);                         \
  __builtin_amdgcn_s_setprio(0);
#define BAR() asm volatile("s_barrier" ::: "memory")
#define LGKM0()                                                              \
  asm volatile("s_waitcnt lgkmcnt(0)" ::: "memory");                         \
  __builtin_amdgcn_sched_barrier(0)

  int4 pbC0, pbC1, pbC2, pbC3, pbN0, pbN1, pbN2, pbN3;

  // ---- prologue: tiles 0 (LDS) and 1 (A->LDS buf1, B->pbC regs) ----
  {
    gl16(aSrc, aDst);                                 // tile0 -> Abuf0
    gl16(aSrc + 131072, aDst + 256);
    gl16(aSrc + 128, aDst + 4096);                    // tile1 -> Abuf1
    gl16(aSrc + 128 + 131072, aDst + 4096 + 256);
    int4 q0 = *(const int4*)(bSrc + c0 * 4);
    int4 q1 = *(const int4*)(bSrc + c0 * 4 + 4);
    int4 q2 = *(const int4*)(bSrc + (c0 + 4) * 4);
    int4 q3 = *(const int4*)(bSrc + (c0 + 4) * 4 + 4);
    stB(0, c0, q0); stB(0, c0 + 1, q1); stB(0, c0 + 4, q2); stB(0, c0 + 5, q3);
    const int* b1 = bSrc + 32;
    pbC0 = *(const int4*)(b1 + c0 * 4);
    pbC1 = *(const int4*)(b1 + c0 * 4 + 4);
    pbC2 = *(const int4*)(b1 + (c0 + 4) * 4);
    pbC3 = *(const int4*)(b1 + (c0 + 4) * 4 + 4);
    asm volatile("s_waitcnt vmcnt(0) lgkmcnt(0)" ::: "memory");
    BAR();
  }

  // ---- steady state: t = 0 .. TILES-3 (issues staging for t+2) ----
  for (int t = 0; t <= TILES - 3; ++t) {
    const int AO = (t & 3) * 4096, BO = (t & 1) * 8192;
    const int AOs = ((t + 2) & 3) * 4096, BOw = ((t + 1) & 1) * 8192;
    bf16x8 av[4], bv[4];
    // phase 0: issue pb(t+2); read kh=0; compute
    const int* bs = bSrc + (t + 2) * 32;
    pbN0 = *(const int4*)(bs + c0 * 4);
    pbN1 = *(const int4*)(bs + c0 * 4 + 4);
    pbN2 = *(const int4*)(bs + (c0 + 4) * 4);
    pbN3 = *(const int4*)(bs + (c0 + 4) * 4 + 4);
    DSREAD(0, AO, BO);
    BAR(); LGKM0();
    MFMA16();
    BAR();
    // phase 1: issue gl16(t+2); write B(t+1); read kh=1; compute
    const char* as = aSrc + (size_t)(t + 2) * 128;
    gl16(as, aDst + AOs);
    gl16(as + 131072, aDst + AOs + 256);
    stB(BOw, c0, pbC0); stB(BOw, c0 + 1, pbC1);
    stB(BOw, c0 + 4, pbC2); stB(BOw, c0 + 5, pbC3);
    DSREAD(1, AO, BO);
    BAR(); LGKM0();
    MFMA16();
    asm volatile("s_waitcnt vmcnt(6)" ::: "memory");  // gl16(t+1) landed
    BAR();                                            // tile boundary
    pbC0 = pbN0; pbC1 = pbN1; pbC2 = pbN2; pbC3 = pbN3;
  }

  // ---- t = TILES-2: no new staging; write B(TILES-1) ----
  {
    const int AO = ((TILES - 2) & 3) * 4096, BO = ((TILES - 2) & 1) * 8192;
    const int BOw = ((TILES - 1) & 1) * 8192;
    bf16x8 av[4], bv[4];
    DSREAD(0, AO, BO);
    BAR(); LGKM0();
    MFMA16();
    BAR();
    stB(BOw, c0, pbC0); stB(BOw, c0 + 1, pbC1);
    stB(BOw, c0 + 4, pbC2); stB(BOw, c0 + 5, pbC3);
    DSREAD(1, AO, BO);
    BAR(); LGKM0();
    MFMA16();
    asm volatile("s_waitcnt vmcnt(0)" ::: "memory");  // gl16(TILES-1) landed
    BAR();
  }
  // ---- t = TILES-1: compute only ----
  {
    const int AO = ((TILES - 1) & 3) * 4096, BO = ((TILES - 1) & 1) * 8192;
    bf16x8 av[4], bv[4];
    DSREAD(0, AO, BO);
    BAR(); LGKM0();
    MFMA16();
    BAR();
    DSREAD(1, AO, BO);
    LGKM0();
    MFMA16();
  }

  // epilogue: C/D layout col=lane&15, row=(lane>>4)*4+reg
  const int omb = m0 + wm * 64 + lq * 4;
  const int on = n0 + wn * 64 + lr;
  float scv[4];
#pragma unroll
  for (int fn = 0; fn < 4; ++fn) scv[fn] = scale[on + fn * 16];
  float rsv[4][4];
#pragma unroll
  for (int mi = 0; mi < 4; ++mi)
#pragma unroll
    for (int rr = 0; rr < 4; ++rr)
      rsv[mi][rr] = rowsum[ks * BATCH + omb + mi * 16 + rr];

  if (part) {
    float* dst = ks ? part : out;
#pragma unroll
    for (int mi = 0; mi < 4; ++mi)
#pragma unroll
      for (int fn = 0; fn < 4; ++fn) {
        const float s = scv[fn];
        float* op = dst + (size_t)(omb + mi * 16) * OUT_F + (on + fn * 16);
#pragma unroll
        for (int rr = 0; rr < 4; ++rr)
          op[(size_t)rr * OUT_F] = s * (acc[mi][fn][rr] - 136.f * rsv[mi][rr]);
      }
  } else {
#pragma unroll
    for (int mi = 0; mi < 4; ++mi)
#pragma unroll
      for (int fn = 0; fn < 4; ++fn) {
        const float s = scv[fn];
        float* op = out + (size_t)(omb + mi * 16) * OUT_F + (on + fn * 16);
#pragma unroll
        for (int rr = 0; rr < 4; ++rr)
          atomicAdd(op + (size_t)rr * OUT_F, s * (acc[mi][fn][rr] - 136.f * rsv[mi][rr]));
      }
  }
#undef DSREAD
#undef MFMA16
#undef BAR
#undef LGKM0
}

// out += part, grid-strided float4
__global__ __launch_bounds__(256) void reduce_add(float* __restrict__ out,
                                                  const float* __restrict__ part) {
  const size_t n = (size_t)BATCH * OUT_F / 4;
  float4* o4 = (float4*)out;
  const float4* p4 = (const float4*)part;
  for (size_t i = (size_t)blockIdx.x * 256 + threadIdx.x; i < n;
       i += (size_t)gridDim.x * 256) {
    float4 a = o4[i];
    float4 b = p4[i];
    a.x += b.x; a.y += b.y; a.z += b.z; a.w += b.w;
    o4[i] = a;
  }
}

extern "C" void kernel_launch(void* const* d_in, const int* in_sizes, int n_in,
                              void* d_out, int out_size, void* d_ws, size_t ws_size,
                              hipStream_t stream) {
  const float* x = (const float*)d_in[0];
  const int* pw = (const int*)d_in[1];
  const float* scale = (const float*)d_in[2];
  float* out = (float*)d_out;

  ushort* xb = (ushort*)d_ws;  // 8 MiB
  float* rowsum = (float*)((char*)d_ws + (size_t)8 * 1024 * 1024);  // 2x512 f32
  const size_t need = (size_t)8 * 1024 * 1024 + 65536 + (size_t)BATCH * OUT_F * 4;
  float* part = (ws_size >= need)
      ? (float*)((char*)d_ws + (size_t)8 * 1024 * 1024 + 65536)
      : nullptr;

  cvt_rowsum<<<BATCH, 256, 0, stream>>>(x, xb, rowsum, part ? nullptr : out);
  dim3 grid(OUT_F / BN, BATCH / BM, KSPLIT);
  qgemm<<<grid, 512, 0, stream>>>(xb, pw, scale, rowsum, out, part);
  if (part) reduce_add<<<2048, 256, 0, stream>>>(out, part);
}

// Round 6
// 284.867 us; speedup vs baseline: 1.0705x; 1.0705x over previous
//
#include <hip/hip_runtime.h>
#include <cstdint>
#include <cstddef>

#define IN_F 8192
#define OUT_F 8192
#define BATCH 512
#define KSPLIT 4
#define KSLICE (IN_F / KSPLIT) /* 2048 */
#define BK 32
#define TILES (KSLICE / BK) /* 64 */
#define BM 256
#define BN 256

typedef __bf16 bf16x8 __attribute__((ext_vector_type(8)));
typedef float floatx4 __attribute__((ext_vector_type(4)));

// fp32 -> bf16 round-to-nearest-even
__device__ __forceinline__ ushort f2bf(float f) {
  uint32_t u = __float_as_uint(f);
  u += 0x7FFFu + ((u >> 16) & 1u);
  return (ushort)(u >> 16);
}

// packed int (2 nibbles in low byte) -> bf16x2 of biased weights (q+136):
// low half = 0x4300|hi_nib (even k), high half = 0x4300|lo_nib (odd k)
// 3-VALU form: a = u|(u<<20); r = ((a>>4) & 0x000F000F) | 0x43004300
__device__ __forceinline__ uint32_t dq(uint32_t u) {
  return (((u | (u << 20)) >> 4) & 0x000F000Fu) | 0x43004300u;
}

// async global->LDS, 16B/lane, LDS dest = wave-uniform base + lane*16
__device__ __forceinline__ void gl16(const void* g, uint32_t* l) {
  __builtin_amdgcn_global_load_lds(
      (const __attribute__((address_space(1))) uint32_t*)g,
      (__attribute__((address_space(3))) uint32_t*)l, 16, 0, 0);
}

// Pass 1: x fp32 -> bf16, per-slice rowsums (KSPLIT=4). Zeroes out only on
// the atomic-fallback path (zout != nullptr).
__global__ __launch_bounds__(256) void cvt_rowsum(const float* __restrict__ x,
                                                  ushort* __restrict__ xb,
                                                  float* __restrict__ rowsum,
                                                  float* __restrict__ zout) {
  const int b = blockIdx.x;
  const int t = threadIdx.x;
  const float4* xr = (const float4*)(x + (size_t)b * IN_F);
  ushort4* xo = (ushort4*)(xb + (size_t)b * IN_F);
  float s[4] = {0.f, 0.f, 0.f, 0.f};
#pragma unroll
  for (int i = 0; i < 8; ++i) {
    float4 v = xr[i * 256 + t];
    ushort4 o;
    o.x = f2bf(v.x); o.y = f2bf(v.y); o.z = f2bf(v.z); o.w = f2bf(v.w);
    xo[i * 256 + t] = o;
    if (zout) {
      float4 z = {0.f, 0.f, 0.f, 0.f};
      ((float4*)(zout + (size_t)b * OUT_F))[i * 256 + t] = z;
    }
    s[i >> 1] += __uint_as_float((uint32_t)o.x << 16) + __uint_as_float((uint32_t)o.y << 16)
               + __uint_as_float((uint32_t)o.z << 16) + __uint_as_float((uint32_t)o.w << 16);
  }
  __shared__ float red[4][4];
  const int lane = t & 63, wid = t >> 6;
#pragma unroll
  for (int j = 0; j < 4; ++j) {
    float v = s[j];
#pragma unroll
    for (int off = 32; off >= 1; off >>= 1) v += __shfl_down(v, off, 64);
    if (lane == 0) red[wid][j] = v;
  }
  __syncthreads();
  if (t < 4) rowsum[t * BATCH + b] = red[0][t] + red[1][t] + red[2][t] + red[3][t];
}

// Split-K(4) quantized GEMM, 256(m) x 256(n) x (BK=32), 512 thr, 8 waves
// (2m x 4n), per-wave 128x64 (acc[8][4], 42.7 FLOP/LDS-byte -> MFMA-bound).
// BOTH A (bf16) and B (packed int4, 2B/weight == bf16 bytes!) staged by
// global_load_lds into 4 rotating 16KB slots each; B dequanted IN-REGISTER
// after ds_read (no ds_writes anywhere -> no write conflicts, clean lgkm).
// 2-tile lookahead, vmcnt(4) counted waits only (never 0 in main loop).
// LDS rows = 64B = 4 chunks; swizzle chunk' = chunk ^ ((row>>1)&3):
// exactly 2-way on b128 reads (free), linear for gl16 (fold into source).
__global__ __launch_bounds__(512, 2) void qgemm(const ushort* __restrict__ xb,
                                                const int* __restrict__ pw,
                                                const float* __restrict__ scale,
                                                const float* __restrict__ rowsum,
                                                float* __restrict__ out,
                                                float* __restrict__ part) {
  __shared__ uint32_t As[4 * 256 * 16];  // 4 slots x 16 KB = 64 KB
  __shared__ uint32_t Bs[4 * 256 * 16];  // 64 KB

  const int tid = threadIdx.x;
  const int lane = tid & 63;
  const int w = tid >> 6;
  const int wm = w >> 2, wn = w & 3;
  const int lr = lane & 15, lq = lane >> 4;

  const int n0 = blockIdx.x * BN;
  const int m0 = blockIdx.y * BM;
  const int ks = blockIdx.z;

  // gl16 source: lane l -> (row base+ (l>>2), pos l&3); stored chunk at
  // (row,p) is p ^ ((row>>1)&3) -> fetch logical chunk (l&3)^((l>>3)&3).
  const int swz = ((lane & 3) ^ ((lane >> 3) & 3)) * 16;
  const char* aSrc0 = (const char*)xb
      + (size_t)(m0 + w * 32 + (lane >> 2)) * (IN_F * 2)
      + (size_t)ks * (KSLICE * 2) + swz;
  const char* bSrc0 = (const char*)pw
      + (size_t)(n0 + w * 32 + (lane >> 2)) * (IN_F * 2)  // row = IN_F/2 ints = same bytes
      + (size_t)ks * (KSLICE * 2) + swz;
  uint32_t* aD = As + w * 512;  // + slot*4096 + j*256
  uint32_t* bD = Bs + w * 512;

  // fragment read offsets: row = mtile + lr, chunk p = lq ^ ((lr>>1)&3)
  const int key = (lr >> 1) & 3;
  const int aBase = wm * 2048 + lr * 16 + ((lq ^ key) * 4);  // + mh*1024 + f*256
  const int bBase = wn * 1024 + lr * 16 + ((lq ^ key) * 4);  // + f*256

  floatx4 acc[8][4] = {};

#define BAR() asm volatile("s_barrier" ::: "memory")
#define LGKM0()                                                              \
  asm volatile("s_waitcnt lgkmcnt(0)" ::: "memory");                         \
  __builtin_amdgcn_sched_barrier(0)
#define VMW(n) asm volatile("s_waitcnt vmcnt(" #n ")" ::: "memory")

  // ---- prologue: stage tiles 0,1 into slots 0,1 (8 gl16/wave) ----
  gl16(aSrc0, aD);              gl16(aSrc0 + 262144, aD + 256);
  gl16(bSrc0, bD);              gl16(bSrc0 + 262144, bD + 256);
  gl16(aSrc0 + 64, aD + 4096);  gl16(aSrc0 + 64 + 262144, aD + 4096 + 256);
  gl16(bSrc0 + 64, bD + 4096);  gl16(bSrc0 + 64 + 262144, bD + 4096 + 256);
  VMW(4);  // tile 0 landed; tile 1's 4 still in flight
  BAR();

  bf16x8 av[4], bv[4];
  int4 pb[4];

  for (int t = 0; t <= TILES - 3; ++t) {
    const int slot = (t & 3) * 4096, wsl = ((t + 2) & 3) * 4096;
    const char* as = aSrc0 + (size_t)(t + 2) * 64;
    const char* bs = bSrc0 + (size_t)(t + 2) * 64;
    // ---- phase 0: read B(packed)+A(mh0); issue A(t+2); MFMA mh0 ----
#pragma unroll
    for (int f = 0; f < 4; ++f)
      pb[f] = *(const int4*)(Bs + slot + bBase + f * 256);
#pragma unroll
    for (int f = 0; f < 4; ++f)
      av[f] = *(const bf16x8*)(As + slot + aBase + f * 256);
    gl16(as, aD + wsl);
    gl16(as + 262144, aD + wsl + 256);
    BAR();
    LGKM0();
#pragma unroll
    for (int f = 0; f < 4; ++f) {
      int4 u;
      u.x = (int)dq((uint32_t)pb[f].x); u.y = (int)dq((uint32_t)pb[f].y);
      u.z = (int)dq((uint32_t)pb[f].z); u.w = (int)dq((uint32_t)pb[f].w);
      bv[f] = *(const bf16x8*)&u;
    }
    __builtin_amdgcn_s_setprio(1);
#pragma unroll
    for (int fm = 0; fm < 4; ++fm)
#pragma unroll
      for (int fn = 0; fn < 4; ++fn)
        acc[fm][fn] = __builtin_amdgcn_mfma_f32_16x16x32_bf16(av[fm], bv[fn],
                                                              acc[fm][fn], 0, 0, 0);
    __builtin_amdgcn_s_setprio(0);
    BAR();
    // ---- phase 1: read A(mh1); issue B(t+2); MFMA mh1 ----
#pragma unroll
    for (int f = 0; f < 4; ++f)
      av[f] = *(const bf16x8*)(As + slot + aBase + 1024 + f * 256);
    gl16(bs, bD + wsl);
    gl16(bs + 262144, bD + wsl + 256);
    BAR();
    LGKM0();
    __builtin_amdgcn_s_setprio(1);
#pragma unroll
    for (int fm = 0; fm < 4; ++fm)
#pragma unroll
      for (int fn = 0; fn < 4; ++fn)
        acc[4 + fm][fn] = __builtin_amdgcn_mfma_f32_16x16x32_bf16(av[fm], bv[fn],
                                                                  acc[4 + fm][fn], 0, 0, 0);
    __builtin_amdgcn_s_setprio(0);
    VMW(4);  // tile t+1's 4 gloads retired; t+2's 4 stay in flight
    BAR();
  }

  // ---- t = TILES-2: no staging; vmcnt(0) covered by a full tile ----
  {
    const int slot = ((TILES - 2) & 3) * 4096;
#pragma unroll
    for (int f = 0; f < 4; ++f)
      pb[f] = *(const int4*)(Bs + slot + bBase + f * 256);
#pragma unroll
    for (int f = 0; f < 4; ++f)
      av[f] = *(const bf16x8*)(As + slot + aBase + f * 256);
    BAR();
    LGKM0();
#pragma unroll
    for (int f = 0; f < 4; ++f) {
      int4 u;
      u.x = (int)dq((uint32_t)pb[f].x); u.y = (int)dq((uint32_t)pb[f].y);
      u.z = (int)dq((uint32_t)pb[f].z); u.w = (int)dq((uint32_t)pb[f].w);
      bv[f] = *(const bf16x8*)&u;
    }
#pragma unroll
    for (int fm = 0; fm < 4; ++fm)
#pragma unroll
      for (int fn = 0; fn < 4; ++fn)
        acc[fm][fn] = __builtin_amdgcn_mfma_f32_16x16x32_bf16(av[fm], bv[fn],
                                                              acc[fm][fn], 0, 0, 0);
    BAR();
#pragma unroll
    for (int f = 0; f < 4; ++f)
      av[f] = *(const bf16x8*)(As + slot + aBase + 1024 + f * 256);
    LGKM0();
#pragma unroll
    for (int fm = 0; fm < 4; ++fm)
#pragma unroll
      for (int fn = 0; fn < 4; ++fn)
        acc[4 + fm][fn] = __builtin_amdgcn_mfma_f32_16x16x32_bf16(av[fm], bv[fn],
                                                                  acc[4 + fm][fn], 0, 0, 0);
    VMW(0);  // tile TILES-1 landed
    BAR();
  }
  // ---- t = TILES-1: compute only ----
  {
    const int slot = ((TILES - 1) & 3) * 4096;
#pragma unroll
    for (int f = 0; f < 4; ++f)
      pb[f] = *(const int4*)(Bs + slot + bBase + f * 256);
#pragma unroll
    for (int f = 0; f < 4; ++f)
      av[f] = *(const bf16x8*)(As + slot + aBase + f * 256);
    LGKM0();
#pragma unroll
    for (int f = 0; f < 4; ++f) {
      int4 u;
      u.x = (int)dq((uint32_t)pb[f].x); u.y = (int)dq((uint32_t)pb[f].y);
      u.z = (int)dq((uint32_t)pb[f].z); u.w = (int)dq((uint32_t)pb[f].w);
      bv[f] = *(const bf16x8*)&u;
    }
#pragma unroll
    for (int fm = 0; fm < 4; ++fm)
#pragma unroll
      for (int fn = 0; fn < 4; ++fn)
        acc[fm][fn] = __builtin_amdgcn_mfma_f32_16x16x32_bf16(av[fm], bv[fn],
                                                              acc[fm][fn], 0, 0, 0);
#pragma unroll
    for (int f = 0; f < 4; ++f)
      av[f] = *(const bf16x8*)(As + slot + aBase + 1024 + f * 256);
    LGKM0();
#pragma unroll
    for (int fm = 0; fm < 4; ++fm)
#pragma unroll
      for (int fn = 0; fn < 4; ++fn)
        acc[4 + fm][fn] = __builtin_amdgcn_mfma_f32_16x16x32_bf16(av[fm], bv[fn],
                                                                  acc[4 + fm][fn], 0, 0, 0);
  }

  // epilogue: C/D layout col=lane&15, row=(lane>>4)*4+reg
  const int omb = m0 + wm * 128 + lq * 4;
  const int on = n0 + wn * 64 + lr;
  float scv[4];
#pragma unroll
  for (int fn = 0; fn < 4; ++fn) scv[fn] = scale[on + fn * 16];
  float rsv[8][4];
#pragma unroll
  for (int fmg = 0; fmg < 8; ++fmg)
#pragma unroll
    for (int rr = 0; rr < 4; ++rr)
      rsv[fmg][rr] = rowsum[ks * BATCH + omb + fmg * 16 + rr];

  if (part) {
    float* dst = (ks == 0) ? out : (part + (size_t)(ks - 1) * BATCH * OUT_F);
#pragma unroll
    for (int fmg = 0; fmg < 8; ++fmg)
#pragma unroll
      for (int fn = 0; fn < 4; ++fn) {
        const float s = scv[fn];
        float* op = dst + (size_t)(omb + fmg * 16) * OUT_F + (on + fn * 16);
#pragma unroll
        for (int rr = 0; rr < 4; ++rr)
          op[(size_t)rr * OUT_F] = s * (acc[fmg][fn][rr] - 136.f * rsv[fmg][rr]);
      }
  } else {
#pragma unroll
    for (int fmg = 0; fmg < 8; ++fmg)
#pragma unroll
      for (int fn = 0; fn < 4; ++fn) {
        const float s = scv[fn];
        float* op = out + (size_t)(omb + fmg * 16) * OUT_F + (on + fn * 16);
#pragma unroll
        for (int rr = 0; rr < 4; ++rr)
          atomicAdd(op + (size_t)rr * OUT_F, s * (acc[fmg][fn][rr] - 136.f * rsv[fmg][rr]));
      }
  }
#undef BAR
#undef LGKM0
#undef VMW
}

// out += p0 + p1 + p2, grid-strided float4
__global__ __launch_bounds__(256) void reduce_add(float* __restrict__ out,
                                                  const float* __restrict__ part) {
  const size_t n = (size_t)BATCH * OUT_F / 4;
  float4* o4 = (float4*)out;
  const float4* p0 = (const float4*)part;
  const float4* p1 = p0 + n;
  const float4* p2 = p1 + n;
  for (size_t i = (size_t)blockIdx.x * 256 + threadIdx.x; i < n;
       i += (size_t)gridDim.x * 256) {
    float4 a = o4[i];
    float4 b = p0[i], c = p1[i], d = p2[i];
    a.x += b.x + c.x + d.x;
    a.y += b.y + c.y + d.y;
    a.z += b.z + c.z + d.z;
    a.w += b.w + c.w + d.w;
    o4[i] = a;
  }
}

extern "C" void kernel_launch(void* const* d_in, const int* in_sizes, int n_in,
                              void* d_out, int out_size, void* d_ws, size_t ws_size,
                              hipStream_t stream) {
  const float* x = (const float*)d_in[0];
  const int* pw = (const int*)d_in[1];
  const float* scale = (const float*)d_in[2];
  float* out = (float*)d_out;

  ushort* xb = (ushort*)d_ws;  // 8 MiB
  float* rowsum = (float*)((char*)d_ws + (size_t)8 * 1024 * 1024);  // 4x512 f32
  const size_t need = (size_t)8 * 1024 * 1024 + 65536
      + (size_t)3 * BATCH * OUT_F * sizeof(float);  // ~56.3 MB
  float* part = (ws_size >= need)
      ? (float*)((char*)d_ws + (size_t)8 * 1024 * 1024 + 65536)
      : nullptr;

  cvt_rowsum<<<BATCH, 256, 0, stream>>>(x, xb, rowsum, part ? nullptr : out);
  dim3 grid(OUT_F / BN, BATCH / BM, KSPLIT);
  qgemm<<<grid, 512, 0, stream>>>(xb, pw, scale, rowsum, out, part);
  if (part) reduce_add<<<2048, 256, 0, stream>>>(out, part);
}

// Round 7
// 277.906 us; speedup vs baseline: 1.0973x; 1.0250x over previous
//
#include <hip/hip_runtime.h>
#include <cstdint>
#include <cstddef>

#define IN_F 8192
#define OUT_F 8192
#define BATCH 512
#define KSPLIT 4
#define KSLICE (IN_F / KSPLIT) /* 2048 */
#define BK 32
#define TILES (KSLICE / BK) /* 64 */
#define BM 256
#define BN 256

typedef __bf16 bf16x8 __attribute__((ext_vector_type(8)));
typedef float floatx4 __attribute__((ext_vector_type(4)));

// fp32 -> bf16 round-to-nearest-even
__device__ __forceinline__ ushort f2bf(float f) {
  uint32_t u = __float_as_uint(f);
  u += 0x7FFFu + ((u >> 16) & 1u);
  return (ushort)(u >> 16);
}

// packed int (2 nibbles in low byte) -> bf16x2 of biased weights (q+136):
// low half = 0x4300|hi_nib (even k), high half = 0x4300|lo_nib (odd k)
__device__ __forceinline__ uint32_t dq(uint32_t u) {
  return (((u | (u << 20)) >> 4) & 0x000F000Fu) | 0x43004300u;
}

// 4 packed ints (16B, one B-fragment) -> bf16x8 biased weight fragment
__device__ __forceinline__ bf16x8 dq8(int4 p) {
  int4 u;
  u.x = (int)dq((uint32_t)p.x); u.y = (int)dq((uint32_t)p.y);
  u.z = (int)dq((uint32_t)p.z); u.w = (int)dq((uint32_t)p.w);
  return *(bf16x8*)&u;
}

// async global->LDS, 16B/lane, LDS dest = wave-uniform base + lane*16
__device__ __forceinline__ void gl16(const void* g, uint32_t* l) {
  __builtin_amdgcn_global_load_lds(
      (const __attribute__((address_space(1))) uint32_t*)g,
      (__attribute__((address_space(3))) uint32_t*)l, 16, 0, 0);
}

// Pass 1: x fp32 -> bf16, per-slice rowsums (KSPLIT=4). Zeroes out only on
// the atomic-fallback path (zout != nullptr).
__global__ __launch_bounds__(256) void cvt_rowsum(const float* __restrict__ x,
                                                  ushort* __restrict__ xb,
                                                  float* __restrict__ rowsum,
                                                  float* __restrict__ zout) {
  const int b = blockIdx.x;
  const int t = threadIdx.x;
  const float4* xr = (const float4*)(x + (size_t)b * IN_F);
  ushort4* xo = (ushort4*)(xb + (size_t)b * IN_F);
  float s[4] = {0.f, 0.f, 0.f, 0.f};
#pragma unroll
  for (int i = 0; i < 8; ++i) {
    float4 v = xr[i * 256 + t];
    ushort4 o;
    o.x = f2bf(v.x); o.y = f2bf(v.y); o.z = f2bf(v.z); o.w = f2bf(v.w);
    xo[i * 256 + t] = o;
    if (zout) {
      float4 z = {0.f, 0.f, 0.f, 0.f};
      ((float4*)(zout + (size_t)b * OUT_F))[i * 256 + t] = z;
    }
    s[i >> 1] += __uint_as_float((uint32_t)o.x << 16) + __uint_as_float((uint32_t)o.y << 16)
               + __uint_as_float((uint32_t)o.z << 16) + __uint_as_float((uint32_t)o.w << 16);
  }
  __shared__ float red[4][4];
  const int lane = t & 63, wid = t >> 6;
#pragma unroll
  for (int j = 0; j < 4; ++j) {
    float v = s[j];
#pragma unroll
    for (int off = 32; off >= 1; off >>= 1) v += __shfl_down(v, off, 64);
    if (lane == 0) red[wid][j] = v;
  }
  __syncthreads();
  if (t < 4) rowsum[t * BATCH + b] = red[0][t] + red[1][t] + red[2][t] + red[3][t];
}

// Split-K(4) quantized GEMM, 256(m) x 256(n) x (BK=32), 512 thr, 8 waves
// (2m x 4n), per-wave 128x64 (acc[8][4]).
// KEY CHANGE vs r6: B NEVER TOUCHES LDS. A 16x16x32 B-fragment is 16
// CONTIGUOUS bytes of packed int4 (2B/weight) -> each wave global-loads its
// own fragments (dwordx4) into regs 2 tiles ahead and dequants in-register.
// LDS serves only A (the truly-shared operand), staged by gl16 into 4
// rotating 16KB slots (depth-2). ONE barrier + ONE counted vmcnt(6) per
// tile; B-dequant is vmcnt-covered, off the lgkm critical path. This
// removes the LDS-region/MFMA-region lockstep serialization seen r0-r6
// (MFMA 28us + VALU 26us + LDS 30us summed to the 122us wall).
// A XOR swizzle (slot = chunk ^ ((row>>1)&3)) verbatim from r6: 0 conflicts.
__global__ __launch_bounds__(512, 2) void qgemm(const ushort* __restrict__ xb,
                                                const int* __restrict__ pw,
                                                const float* __restrict__ scale,
                                                const float* __restrict__ rowsum,
                                                float* __restrict__ out,
                                                float* __restrict__ part) {
  __shared__ uint32_t As[4 * 256 * 16];  // 4 slots x 16 KB = 64 KB

  const int tid = threadIdx.x;
  const int lane = tid & 63;
  const int w = tid >> 6;
  const int wm = w >> 2, wn = w & 3;
  const int lr = lane & 15, lq = lane >> 4;

  const int n0 = blockIdx.x * BN;
  const int m0 = blockIdx.y * BM;
  const int ks = blockIdx.z;

  // A gl16 source (r6 verbatim): lane l -> row base+(l>>2), pos l&3; stored
  // chunk at (row,p) is p ^ ((row>>1)&3) -> fold key (l>>3)&3 into source.
  const int swz = ((lane & 3) ^ ((lane >> 3) & 3)) * 16;
  const char* aSrc0 = (const char*)xb
      + (size_t)(m0 + w * 32 + (lane >> 2)) * (IN_F * 2)
      + (size_t)ks * (KSLICE * 2) + swz;

  // B fragment pointers: frag f lives at row n0+wn*64+f*16+lr, 16B at col
  // lq*16 (+ t*64 per tile). Packed row = IN_F*2 bytes (2B/weight).
  const char* bbase = (const char*)pw + (size_t)(n0 + wn * 64 + lr) * (IN_F * 2)
      + (size_t)ks * (KSLICE * 2) + lq * 16;
  const char* bp0 = bbase;
  const char* bp1 = bbase + (size_t)16 * (IN_F * 2);
  const char* bp2 = bbase + (size_t)32 * (IN_F * 2);
  const char* bp3 = bbase + (size_t)48 * (IN_F * 2);

  // A fragment read offsets: row = wm*128 + f*16 + lr, chunk lq ^ ((lr>>1)&3)
  const int key = (lr >> 1) & 3;
  const int aBase = wm * 2048 + lr * 16 + ((lq ^ key) * 4);  // + f*256

  floatx4 acc[8][4] = {};

#define VMW6() asm volatile("s_waitcnt vmcnt(6)" ::: "memory")
#define VMW0() asm volatile("s_waitcnt vmcnt(0)" ::: "memory")
#define BAR() asm volatile("s_barrier" ::: "memory")

  // One K-tile. P0..P3: packed B(tt) in regs (consumed, then refilled with
  // B(tt+2) when ISS). A(tt) is published in slot tt&3 at entry.
#define TILE(tt, P0, P1, P2, P3, ISS)                                        \
  {                                                                          \
    const uint32_t* sA = As + (((tt) & 3) * 4096) + aBase;                   \
    bf16x8 av[4], bv[4];                                                     \
    bv[0] = dq8(P0); bv[1] = dq8(P1); bv[2] = dq8(P2); bv[3] = dq8(P3);      \
    _Pragma("unroll") for (int f = 0; f < 4; ++f)                            \
        av[f] = *(const bf16x8*)(sA + f * 256);                              \
    if (ISS) {                                                               \
      const size_t co = (size_t)((tt) + 2) * 64;                             \
      P0 = *(const int4*)(bp0 + co); P1 = *(const int4*)(bp1 + co);          \
      P2 = *(const int4*)(bp2 + co); P3 = *(const int4*)(bp3 + co);          \
      const char* as_ = aSrc0 + co;                                          \
      uint32_t* ad_ = As + ((((tt) + 2) & 3) * 4096) + w * 512;              \
      gl16(as_, ad_);                                                        \
      gl16(as_ + 262144, ad_ + 256);                                         \
    }                                                                        \
    __builtin_amdgcn_s_setprio(1);                                           \
    _Pragma("unroll") for (int f = 0; f < 4; ++f)                            \
        _Pragma("unroll") for (int fn = 0; fn < 4; ++fn)                     \
            acc[f][fn] = __builtin_amdgcn_mfma_f32_16x16x32_bf16(            \
                av[f], bv[fn], acc[f][fn], 0, 0, 0);                         \
    __builtin_amdgcn_s_setprio(0);                                           \
    _Pragma("unroll") for (int f = 0; f < 4; ++f)                            \
        av[f] = *(const bf16x8*)(sA + 1024 + f * 256);                       \
    __builtin_amdgcn_s_setprio(1);                                           \
    _Pragma("unroll") for (int f = 0; f < 4; ++f)                            \
        _Pragma("unroll") for (int fn = 0; fn < 4; ++fn)                     \
            acc[4 + f][fn] = __builtin_amdgcn_mfma_f32_16x16x32_bf16(        \
                av[f], bv[fn], acc[4 + f][fn], 0, 0, 0);                     \
    __builtin_amdgcn_s_setprio(0);                                           \
  }

  int4 pE0, pE1, pE2, pE3, pO0, pO1, pO2, pO3;

  // ---- prologue: B(0)->E, A(0)->slot0, B(1)->O, A(1)->slot1 ----
  {
    uint32_t* aD = As + w * 512;
    pE0 = *(const int4*)(bp0); pE1 = *(const int4*)(bp1);
    pE2 = *(const int4*)(bp2); pE3 = *(const int4*)(bp3);
    gl16(aSrc0, aD);
    gl16(aSrc0 + 262144, aD + 256);
    pO0 = *(const int4*)(bp0 + 64); pO1 = *(const int4*)(bp1 + 64);
    pO2 = *(const int4*)(bp2 + 64); pO3 = *(const int4*)(bp3 + 64);
    gl16(aSrc0 + 64, aD + 4096);
    gl16(aSrc0 + 64 + 262144, aD + 4096 + 256);
    VMW6();  // oldest 6 = B(0)+A(0) landed; B(1)+A(1) stay in flight
    BAR();
  }

  // ---- steady state: tiles 0..61 all issue prefetch for t+2 ----
  for (int t = 0; t <= TILES - 4; t += 2) {
    TILE(t, pE0, pE1, pE2, pE3, true);
    VMW6();  // B(t+1)+A(t+1) landed; t+2's 6 ops in flight
    BAR();
    TILE(t + 1, pO0, pO1, pO2, pO3, true);
    VMW6();
    BAR();
  }
  // ---- tail: tiles 62 (even,E) and 63 (odd,O), no new staging ----
  TILE(TILES - 2, pE0, pE1, pE2, pE3, false);
  VMW0();  // drain B(63)+A(63)
  BAR();
  TILE(TILES - 1, pO0, pO1, pO2, pO3, false);

  // epilogue: C/D layout col=lane&15, row=(lane>>4)*4+reg
  const int omb = m0 + wm * 128 + lq * 4;
  const int on = n0 + wn * 64 + lr;
  float scv[4];
#pragma unroll
  for (int fn = 0; fn < 4; ++fn) scv[fn] = scale[on + fn * 16];
  float rsv[8][4];
#pragma unroll
  for (int fmg = 0; fmg < 8; ++fmg)
#pragma unroll
    for (int rr = 0; rr < 4; ++rr)
      rsv[fmg][rr] = rowsum[ks * BATCH + omb + fmg * 16 + rr];

  if (part) {
    float* dst = (ks == 0) ? out : (part + (size_t)(ks - 1) * BATCH * OUT_F);
#pragma unroll
    for (int fmg = 0; fmg < 8; ++fmg)
#pragma unroll
      for (int fn = 0; fn < 4; ++fn) {
        const float s = scv[fn];
        float* op = dst + (size_t)(omb + fmg * 16) * OUT_F + (on + fn * 16);
#pragma unroll
        for (int rr = 0; rr < 4; ++rr)
          op[(size_t)rr * OUT_F] = s * (acc[fmg][fn][rr] - 136.f * rsv[fmg][rr]);
      }
  } else {
#pragma unroll
    for (int fmg = 0; fmg < 8; ++fmg)
#pragma unroll
      for (int fn = 0; fn < 4; ++fn) {
        const float s = scv[fn];
        float* op = out + (size_t)(omb + fmg * 16) * OUT_F + (on + fn * 16);
#pragma unroll
        for (int rr = 0; rr < 4; ++rr)
          atomicAdd(op + (size_t)rr * OUT_F, s * (acc[fmg][fn][rr] - 136.f * rsv[fmg][rr]));
      }
  }
#undef TILE
#undef VMW6
#undef VMW0
#undef BAR
}

// out += p0 + p1 + p2, grid-strided float4
__global__ __launch_bounds__(256) void reduce_add(float* __restrict__ out,
                                                  const float* __restrict__ part) {
  const size_t n = (size_t)BATCH * OUT_F / 4;
  float4* o4 = (float4*)out;
  const float4* p0 = (const float4*)part;
  const float4* p1 = p0 + n;
  const float4* p2 = p1 + n;
  for (size_t i = (size_t)blockIdx.x * 256 + threadIdx.x; i < n;
       i += (size_t)gridDim.x * 256) {
    float4 a = o4[i];
    float4 b = p0[i], c = p1[i], d = p2[i];
    a.x += b.x + c.x + d.x;
    a.y += b.y + c.y + d.y;
    a.z += b.z + c.z + d.z;
    a.w += b.w + c.w + d.w;
    o4[i] = a;
  }
}

extern "C" void kernel_launch(void* const* d_in, const int* in_sizes, int n_in,
                              void* d_out, int out_size, void* d_ws, size_t ws_size,
                              hipStream_t stream) {
  const float* x = (const float*)d_in[0];
  const int* pw = (const int*)d_in[1];
  const float* scale = (const float*)d_in[2];
  float* out = (float*)d_out;

  ushort* xb = (ushort*)d_ws;  // 8 MiB
  float* rowsum = (float*)((char*)d_ws + (size_t)8 * 1024 * 1024);  // 4x512 f32
  const size_t need = (size_t)8 * 1024 * 1024 + 65536
      + (size_t)3 * BATCH * OUT_F * sizeof(float);  // ~56.3 MB
  float* part = (ws_size >= need)
      ? (float*)((char*)d_ws + (size_t)8 * 1024 * 1024 + 65536)
      : nullptr;

  cvt_rowsum<<<BATCH, 256, 0, stream>>>(x, xb, rowsum, part ? nullptr : out);
  dim3 grid(OUT_F / BN, BATCH / BM, KSPLIT);
  qgemm<<<grid, 512, 0, stream>>>(xb, pw, scale, rowsum, out, part);
  if (part) reduce_add<<<2048, 256, 0, stream>>>(out, part);
}